// Round 1
// baseline (243.465 us; speedup 1.0000x reference)
//
#include <hip/hip_runtime.h>

// SpMM: out[i,d] = sum_{e: rows[e]==i} vals[e] * x[cols[e], d]
// N=100000 nodes, E=1600000 edges, DIM=32, fp32.
//
// Baseline: thread per (edge, dim). 32 consecutive lanes = one edge.
//  - x[col] read is a coalesced 128B load per edge-group
//  - rows/cols/vals loads broadcast within the 32-lane group
//  - scatter via fp32 atomicAdd (51.2M atomics total)

#define N_NODES 100000
#define N_EDGES 1600000
#define DIM 32

__global__ __launch_bounds__(256) void spmm_atomic_kernel(
    const int* __restrict__ rows,
    const int* __restrict__ cols,
    const float* __restrict__ vals,
    const float* __restrict__ x,
    float* __restrict__ out)
{
    const long long idx = (long long)blockIdx.x * blockDim.x + threadIdx.x;
    const long long total = (long long)N_EDGES * DIM;
    if (idx >= total) return;

    const int e = (int)(idx >> 5);   // edge index
    const int d = (int)(idx & 31);   // dim index

    const int r   = rows[e];
    const int c   = cols[e];
    const float v = vals[e];

    const float xv = x[(long long)c * DIM + d];
    atomicAdd(&out[(long long)r * DIM + d], v * xv);
}

extern "C" void kernel_launch(void* const* d_in, const int* in_sizes, int n_in,
                              void* d_out, int out_size, void* d_ws, size_t ws_size,
                              hipStream_t stream) {
    const int*   A_rows = (const int*)d_in[0];
    const int*   A_cols = (const int*)d_in[1];
    const float* A_vals = (const float*)d_in[2];
    const float* x      = (const float*)d_in[3];
    float*       out    = (float*)d_out;

    // d_out is poisoned with 0xAA before every timed launch — zero it.
    hipMemsetAsync(out, 0, (size_t)out_size * sizeof(float), stream);

    const long long total = (long long)N_EDGES * DIM;  // 51.2M threads
    const int block = 256;
    const long long grid = (total + block - 1) / block;

    spmm_atomic_kernel<<<(dim3)(unsigned)grid, block, 0, stream>>>(
        A_rows, A_cols, A_vals, x, out);
}